// Round 8
// baseline (623.387 us; speedup 1.0000x reference)
//
#include <hip/hip_runtime.h>
#include <math.h>

#define DIM   128
#define BATCH 16384
#define CTX   10
#define NNEG  10

#define WPB     8                 // waves (rows) per block
#define BLOCK   (WPB * 64)        // 512 threads
#define NBLOCKS (BATCH / WPB)     // 2048

// --- DPP-based add of lane-permuted value (pure VALU, no DS traffic) -------
template <int CTRL>
__device__ __forceinline__ float dpp_add(float v) {
    int r = __builtin_amdgcn_mov_dpp(__float_as_int(v), CTRL, 0xF, 0xF, true);
    return v + __int_as_float(r);
}

// full 64-lane sum, result broadcast to all lanes
__device__ __forceinline__ float wave_sum(float v) {
    v = dpp_add<0xB1>(v);   // quad_perm(1,0,3,2)  : + lane^1
    v = dpp_add<0x4E>(v);   // quad_perm(2,3,0,1)  : + lane^2
    v = dpp_add<0x141>(v);  // row_half_mirror     : + lane^7
    v = dpp_add<0x140>(v);  // row_mirror          : + lane^15
    v += __int_as_float(__builtin_amdgcn_ds_swizzle(__float_as_int(v), 0x401F)); // + lane^16
    v += __shfl_xor(v, 32, 64);                                                  // + lane^32
    return v;
}

// softplus(x) = max(x,0) + log(1 + exp(-|x|)) using HW v_exp/v_log
__device__ __forceinline__ float softplus_fast(float x) {
    return fmaxf(x, 0.0f) + __logf(1.0f + __expf(-fabsf(x)));
}

__global__ __launch_bounds__(BLOCK)
void cbow_fused(const int* __restrict__ pos_u,
                const int* __restrict__ pos_v,
                const int* __restrict__ neg_v,
                const float* __restrict__ u_weight,
                const float* __restrict__ v_weight,
                float* __restrict__ partial,
                unsigned int* __restrict__ counter,
                float* __restrict__ out) {
    const int tid  = threadIdx.x;
    const int wave = tid >> 6;
    const int lane = tid & 63;
    const int row  = blockIdx.x * WPB + wave;
    const int d2   = lane * 2;     // each lane owns 2 consecutive dims

    // ---- wave-uniform indices -> SGPRs (scalar gather bases) --------------
    int ui[CTX], vi[1 + NNEG];
    const int* pu = pos_u + row * CTX;
    #pragma unroll
    for (int c = 0; c < CTX; ++c)
        ui[c] = __builtin_amdgcn_readfirstlane(pu[c]);
    vi[0] = __builtin_amdgcn_readfirstlane(pos_v[row]);
    const int* nv = neg_v + row * NNEG;
    #pragma unroll
    for (int n = 0; n < NNEG; ++n)
        vi[1 + n] = __builtin_amdgcn_readfirstlane(nv[n]);

    // ---- issue all 21 row gathers (independent, max MLP) ------------------
    float2 uu[CTX];
    #pragma unroll
    for (int c = 0; c < CTX; ++c)
        uu[c] = *reinterpret_cast<const float2*>(
            u_weight + (size_t)ui[c] * DIM + d2);
    float2 vv[1 + NNEG];
    #pragma unroll
    for (int k = 0; k < 1 + NNEG; ++k)
        vv[k] = *reinterpret_cast<const float2*>(
            v_weight + (size_t)vi[k] * DIM + d2);

    // ---- emb_u mean -------------------------------------------------------
    float ax = 0.0f, ay = 0.0f;
    #pragma unroll
    for (int c = 0; c < CTX; ++c) { ax += uu[c].x; ay += uu[c].y; }
    ax *= 0.1f; ay *= 0.1f;

    // ---- 11 per-lane partial dots ----------------------------------------
    float p[1 + NNEG];
    #pragma unroll
    for (int k = 0; k < 1 + NNEG; ++k)
        p[k] = ax * vv[k].x + ay * vv[k].y;

    // ---- staged reduction, 11 independent chains per stage (ILP) ----------
    #pragma unroll
    for (int k = 0; k < 1 + NNEG; ++k) p[k] = dpp_add<0xB1>(p[k]);
    #pragma unroll
    for (int k = 0; k < 1 + NNEG; ++k) p[k] = dpp_add<0x4E>(p[k]);
    #pragma unroll
    for (int k = 0; k < 1 + NNEG; ++k) p[k] = dpp_add<0x141>(p[k]);
    #pragma unroll
    for (int k = 0; k < 1 + NNEG; ++k) p[k] = dpp_add<0x140>(p[k]);
    #pragma unroll
    for (int k = 0; k < 1 + NNEG; ++k)
        p[k] += __int_as_float(
            __builtin_amdgcn_ds_swizzle(__float_as_int(p[k]), 0x401F));
    #pragma unroll
    for (int k = 0; k < 1 + NNEG; ++k) p[k] += __shfl_xor(p[k], 32, 64);

    // ---- clip + softplus --------------------------------------------------
    float s0   = fminf(fmaxf(p[0], -10.0f), 10.0f);
    float loss = softplus_fast(-s0);
    #pragma unroll
    for (int n = 1; n <= NNEG; ++n) {
        float sn = fminf(fmaxf(p[n], -10.0f), 10.0f);
        loss += softplus_fast(sn);
    }

    if (lane == 0) partial[row] = loss;

    // ---- deterministic last-block final reduction --------------------------
    __shared__ unsigned int s_old;
    __threadfence();                       // release partial[] device-wide
    __syncthreads();                       // all waves' stores+fences done
    if (tid == 0) s_old = atomicAdd(counter, 1u);
    __syncthreads();
    if (s_old == NBLOCKS - 1) {            // last block: everyone else released
        __threadfence();                   // acquire
        float s = 0.0f;
        #pragma unroll
        for (int i = 0; i < BATCH / BLOCK; ++i)   // 32 strided loads, fixed order
            s += partial[tid + i * BLOCK];
        s = wave_sum(s);
        __shared__ float ls[WPB];
        if (lane == 0) ls[wave] = s;
        __syncthreads();
        if (tid == 0) {
            float t = 0.0f;
            #pragma unroll
            for (int w = 0; w < WPB; ++w) t += ls[w];
            out[0] = t * (1.0f / (float)BATCH);
        }
    }
}

extern "C" void kernel_launch(void* const* d_in, const int* in_sizes, int n_in,
                              void* d_out, int out_size, void* d_ws, size_t ws_size,
                              hipStream_t stream) {
    const int*   pos_u    = (const int*)d_in[0];
    const int*   pos_v    = (const int*)d_in[1];
    const int*   neg_v    = (const int*)d_in[2];
    const float* u_weight = (const float*)d_in[3];
    const float* v_weight = (const float*)d_in[4];
    float* out     = (float*)d_out;
    float* partial = (float*)d_ws;                         // BATCH floats
    unsigned int* counter = (unsigned int*)((char*)d_ws + BATCH * sizeof(float));

    hipMemsetAsync(counter, 0, sizeof(unsigned int), stream);  // graph-capturable
    cbow_fused<<<NBLOCKS, BLOCK, 0, stream>>>(
        pos_u, pos_v, neg_v, u_weight, v_weight, partial, counter, out);
}

// Round 12
// 136.031 us; speedup vs baseline: 4.5827x; 4.5827x over previous
//
#include <hip/hip_runtime.h>
#include <math.h>

#define DIM   128
#define BATCH 16384
#define CTX   10
#define NNEG  10

#define WPB     8                 // waves (rows) per block
#define BLOCK   (WPB * 64)        // 512 threads
#define NBLOCKS (BATCH / WPB)     // 2048

// --- DPP-based add of lane-permuted value (pure VALU, no DS traffic) -------
// NOTE (R8 lesson): NO device-scope __threadfence / single-kernel fusion here.
// With the harness leaving ~256 MB of dirty 0xAA poison in L2/L3, per-block
// device-scope release fences force serialized L2 writebacks (+300 MB HBM
// writes, 15x slowdown). Two plain kernels are the fast structure.
template <int CTRL>
__device__ __forceinline__ float dpp_add(float v) {
    int r = __builtin_amdgcn_mov_dpp(__float_as_int(v), CTRL, 0xF, 0xF, true);
    return v + __int_as_float(r);
}

// full 64-lane sum, result broadcast to all lanes
__device__ __forceinline__ float wave_sum(float v) {
    v = dpp_add<0xB1>(v);   // quad_perm(1,0,3,2)  : + lane^1
    v = dpp_add<0x4E>(v);   // quad_perm(2,3,0,1)  : + lane^2
    v = dpp_add<0x141>(v);  // row_half_mirror     : + lane^7
    v = dpp_add<0x140>(v);  // row_mirror          : + lane^15
    v += __int_as_float(__builtin_amdgcn_ds_swizzle(__float_as_int(v), 0x401F)); // + lane^16
    v += __shfl_xor(v, 32, 64);                                                  // + lane^32
    return v;
}

// softplus(x) = max(x,0) + log(1 + exp(-|x|)) using HW v_exp/v_log
__device__ __forceinline__ float softplus_fast(float x) {
    return fmaxf(x, 0.0f) + __logf(1.0f + __expf(-fabsf(x)));
}

__global__ __launch_bounds__(BLOCK)
void cbow_loss(const int* __restrict__ pos_u,
               const int* __restrict__ pos_v,
               const int* __restrict__ neg_v,
               const float* __restrict__ u_weight,
               const float* __restrict__ v_weight,
               float* __restrict__ partial) {
    const int tid  = threadIdx.x;
    const int wave = tid >> 6;
    const int lane = tid & 63;
    const int row  = blockIdx.x * WPB + wave;
    const int d2   = lane * 2;     // each lane owns 2 consecutive dims

    // ---- wave-uniform indices -> SGPRs (scalar gather bases) --------------
    int ui[CTX], vi[1 + NNEG];
    const int* pu = pos_u + row * CTX;
    #pragma unroll
    for (int c = 0; c < CTX; ++c)
        ui[c] = __builtin_amdgcn_readfirstlane(pu[c]);
    vi[0] = __builtin_amdgcn_readfirstlane(pos_v[row]);
    const int* nv = neg_v + row * NNEG;
    #pragma unroll
    for (int n = 0; n < NNEG; ++n)
        vi[1 + n] = __builtin_amdgcn_readfirstlane(nv[n]);

    // ---- issue all 21 row gathers (independent, max MLP) ------------------
    float2 uu[CTX];
    #pragma unroll
    for (int c = 0; c < CTX; ++c)
        uu[c] = *reinterpret_cast<const float2*>(
            u_weight + (size_t)ui[c] * DIM + d2);
    float2 vv[1 + NNEG];
    #pragma unroll
    for (int k = 0; k < 1 + NNEG; ++k)
        vv[k] = *reinterpret_cast<const float2*>(
            v_weight + (size_t)vi[k] * DIM + d2);

    // ---- emb_u mean -------------------------------------------------------
    float ax = 0.0f, ay = 0.0f;
    #pragma unroll
    for (int c = 0; c < CTX; ++c) { ax += uu[c].x; ay += uu[c].y; }
    ax *= 0.1f; ay *= 0.1f;

    // ---- 11 per-lane partial dots ----------------------------------------
    float p[1 + NNEG];
    #pragma unroll
    for (int k = 0; k < 1 + NNEG; ++k)
        p[k] = ax * vv[k].x + ay * vv[k].y;

    // ---- staged reduction, 11 independent chains per stage (ILP) ----------
    #pragma unroll
    for (int k = 0; k < 1 + NNEG; ++k) p[k] = dpp_add<0xB1>(p[k]);
    #pragma unroll
    for (int k = 0; k < 1 + NNEG; ++k) p[k] = dpp_add<0x4E>(p[k]);
    #pragma unroll
    for (int k = 0; k < 1 + NNEG; ++k) p[k] = dpp_add<0x141>(p[k]);
    #pragma unroll
    for (int k = 0; k < 1 + NNEG; ++k) p[k] = dpp_add<0x140>(p[k]);
    #pragma unroll
    for (int k = 0; k < 1 + NNEG; ++k)
        p[k] += __int_as_float(
            __builtin_amdgcn_ds_swizzle(__float_as_int(p[k]), 0x401F));
    #pragma unroll
    for (int k = 0; k < 1 + NNEG; ++k) p[k] += __shfl_xor(p[k], 32, 64);

    // ---- clip + softplus --------------------------------------------------
    // pos: -log_sigmoid(s) = softplus(-s); neg: -log_sigmoid(-s) = softplus(s)
    float s0   = fminf(fmaxf(p[0], -10.0f), 10.0f);
    float loss = softplus_fast(-s0);
    #pragma unroll
    for (int n = 1; n <= NNEG; ++n) {
        float sn = fminf(fmaxf(p[n], -10.0f), 10.0f);
        loss += softplus_fast(sn);
    }

    if (lane == 0) partial[row] = loss;   // no LDS, no __syncthreads
}

__global__ __launch_bounds__(1024)
void reduce_partials(const float* __restrict__ partial, float* __restrict__ out) {
    const int tid = threadIdx.x;
    // 16384 floats = 1024 threads x 1 float4 x 4 strided passes
    float s = 0.0f;
    #pragma unroll
    for (int i = 0; i < BATCH / (1024 * 4); ++i) {   // 4 x dwordx4 loads
        float4 v = reinterpret_cast<const float4*>(partial)[tid + i * 1024];
        s += (v.x + v.y) + (v.z + v.w);
    }
    s = wave_sum(s);
    __shared__ float ls[16];
    if ((tid & 63) == 0) ls[tid >> 6] = s;
    __syncthreads();
    if (tid == 0) {
        float t = 0.0f;
        #pragma unroll
        for (int w = 0; w < 16; ++w) t += ls[w];
        out[0] = t * (1.0f / (float)BATCH);
    }
}

extern "C" void kernel_launch(void* const* d_in, const int* in_sizes, int n_in,
                              void* d_out, int out_size, void* d_ws, size_t ws_size,
                              hipStream_t stream) {
    const int*   pos_u    = (const int*)d_in[0];
    const int*   pos_v    = (const int*)d_in[1];
    const int*   neg_v    = (const int*)d_in[2];
    const float* u_weight = (const float*)d_in[3];
    const float* v_weight = (const float*)d_in[4];
    float* out     = (float*)d_out;
    float* partial = (float*)d_ws;   // BATCH floats = 64 KiB

    cbow_loss<<<NBLOCKS, BLOCK, 0, stream>>>(
        pos_u, pos_v, neg_v, u_weight, v_weight, partial);
    reduce_partials<<<1, 1024, 0, stream>>>(partial, out);
}